// Round 8
// baseline (1996.842 us; speedup 1.0000x reference)
//
#include <hip/hip_runtime.h>

// GCN pull-mode, round 20. r19 proved barrierless window alignment reaches
// the FETCH floor (98MB ~ 8-XCD compulsory fill) but per-row segment loops
// (1.26 edges/body) starved MLP -> 126us. r18 proved long per-row loops
// drift (row pos ~ k/deg). Round 20: EDGE-CENTRIC SWEEP gets both.
// Bucket edges sorted by src only (key src>>6); csr stores packed
// (dl<<17|src); each block runs ONE long loop over ~2047 edges: 8-lane
// groups gather the full 128B row, accumulate into a 32KB LDS fp32
// accumulator via ds_add_f32. Alignment = equal-work co-resident blocks
// consuming src-sorted lists at equal rate (skew ~ edge-count sigma 2%).
// MLP = 2-way unrolled single loop, 16 gathers in flight/wave.
// DS-atomics (~13us) and VALU (~5us) hide under the ~18us request cap.
// Epilogues unchanged math: in-place f32->f16 conversion then MFMA chains.
//   bbuild: csr packed, src-sorted; dis; xs prescale
//   mega1e: Z2 = dis*(relu(agg64(xs)@W1+b1)@W2)   [782 blk, edge-centric]
//   mega2e: Z3 = dis*(relu(agg64(Z2)+b2)@W3)
//   agg32e: Z4 = dis*(relu(agg32(Z3)+b3)@W4)
//   finale: out = dis*agg16(Z4) + b4
// 7 dispatches.

#define TPB 256
#define NBUCK 782    // ceil(100000/128)
#define BCAP 3072    // fixed slot size; mean 2047, +22 sigma headroom
#define CHUNK 8192   // edges per block in scatter
#define NKEY 2048    // src>>6 (64-node granularity)

typedef __attribute__((ext_vector_type(8))) _Float16 half8;
typedef __attribute__((ext_vector_type(4))) _Float16 half4;
typedef __attribute__((ext_vector_type(4))) float f32x4;

// --- Scatter packed edges into fixed bucket slots ---
__global__ void bscatter_kernel(const int* __restrict__ src, const int* __restrict__ dst,
                                int* __restrict__ bcur, int* __restrict__ bsort, int E) {
    __shared__ int h[NBUCK];
    __shared__ int cur[NBUCK];
    int tid = threadIdx.x;
    for (int i = tid; i < NBUCK; i += blockDim.x) h[i] = 0;
    __syncthreads();
    int base = blockIdx.x * CHUNK;
    int lim = min(base + CHUNK, E);
    for (int e = base + tid; e < lim; e += blockDim.x)
        atomicAdd(&h[dst[e] >> 7], 1);
    __syncthreads();
    for (int i = tid; i < NBUCK; i += blockDim.x)
        cur[i] = h[i] ? (atomicAdd(&bcur[i], h[i]) + i * BCAP) : 0;
    __syncthreads();
    for (int e = base + tid; e < lim; e += blockDim.x) {
        int d = dst[e];
        int pos = atomicAdd(&cur[d >> 7], 1);
        bsort[pos] = ((d & 127) << 17) | src[e];  // src < 2^17
    }
}

// --- Per-bucket counting sort by src>>6 -> src-swept packed csr; dis; prescale.
__global__ __launch_bounds__(256) void bbuild_kernel(
        const int* __restrict__ bcur, const int* __restrict__ bsort,
        int* __restrict__ csr, float* __restrict__ dis,
        const float4* __restrict__ x4, _Float16* __restrict__ xs, int N) {
    __shared__ int ebuf[BCAP];
    __shared__ int obuf[BCAP];
    __shared__ int cnt[NKEY];
    __shared__ int rcnt[128];
    __shared__ float sdis[128];
    __shared__ int wtot[4];
    int b = blockIdx.x;
    int tid = threadIdx.x;
    int ebase = b * BCAP;
    int n = min(bcur[b], BCAP);
#pragma unroll
    for (int j = 0; j < 8; ++j) cnt[tid * 8 + j] = 0;
    if (tid < 128) rcnt[tid] = 0;
    __syncthreads();
    for (int i = tid; i < n; i += 256) {
        int p = bsort[ebase + i];
        ebuf[i] = p;
        atomicAdd(&cnt[(p & 0x1FFFF) >> 6], 1);   // src-only key
        atomicAdd(&rcnt[p >> 17], 1);             // per-dst degree
    }
    __syncthreads();
    // 2048-wide exclusive scan (8 elems/thread + wave scan + cross-wave)
    int w = tid >> 6, lane = tid & 63;
    int loc[8];
    int s = 0;
#pragma unroll
    for (int j = 0; j < 8; ++j) { loc[j] = s; s += cnt[tid * 8 + j]; }
    int v = s;
#pragma unroll
    for (int d = 1; d < 64; d <<= 1) { int u = __shfl_up(v, d, 64); if (lane >= d) v += u; }
    if (lane == 63) wtot[w] = v;
    __syncthreads();
    if (tid == 0) {
        int a = 0;
#pragma unroll
        for (int i = 0; i < 4; ++i) { int t = wtot[i]; wtot[i] = a; a += t; }
    }
    __syncthreads();
    int basep = wtot[w] + (v - s);
    int node0 = b << 7;
    if (tid < 128) {
        int node = node0 + tid;
        float d = 0.f;
        if (node < N) d = rsqrtf((float)rcnt[tid] + 1.0f);
        dis[node] = d;
        sdis[tid] = d;
    }
    __syncthreads();   // all cnt reads done (each thread reads only its own 8)
#pragma unroll
    for (int j = 0; j < 8; ++j) cnt[tid * 8 + j] = basep + loc[j];  // cursors
    __syncthreads();
    for (int i = tid; i < n; i += 256) {
        int p = ebuf[i];
        int pos = atomicAdd(&cnt[(p & 0x1FFFF) >> 6], 1);
        obuf[pos] = p;   // keep full packed record
    }
    __syncthreads();
    for (int i = tid; i < n; i += 256)
        csr[ebase + i] = obuf[i];
    // fused prescale (row-major): xs[node*64 + f] = half(x[node][f] * dis[node])
    for (int i = tid; i < 128 * 16; i += 256) {
        int r = i >> 4, c = i & 15;
        int node = node0 + r;
        if (node >= N) break;
        float d = sdis[r];
        float4 v4 = x4[(size_t)node * 16 + c];
        half4 h;
        h[0] = (_Float16)(v4.x * d); h[1] = (_Float16)(v4.y * d);
        h[2] = (_Float16)(v4.z * d); h[3] = (_Float16)(v4.w * d);
        *(half4*)(xs + (size_t)node * 64 + 4 * c) = h;
    }
}

// Transpose + fp16-convert weights; zero bcur.
// Sections: W1t 96x64 @0, W2t 64x96 @6144, W3t 32x64 @12288, W4t 16x32 @14336.
__global__ void wprep_kernel(const float* __restrict__ W1, const float* __restrict__ W2,
                             const float* __restrict__ W3, const float* __restrict__ W4,
                             _Float16* __restrict__ wt, int* __restrict__ bcur) {
    int t = blockIdx.x * blockDim.x + threadIdx.x;
    if (t < 788) bcur[t] = 0;
    if (t < 6144) {
        int m = t / 64, k = t % 64;
        wt[t] = (_Float16)W1[k * 96 + m];
    } else if (t < 12288) {
        int i = t - 6144; int m = i / 96, k = i % 96;
        wt[t] = (_Float16)W2[k * 64 + m];
    } else if (t < 14336) {
        int i = t - 12288; int m = i / 64, k = i % 64;
        wt[t] = (_Float16)W3[k * 32 + m];
    } else if (t < 14848) {
        int i = t - 14336; int m = i / 32, k = i % 32;
        wt[t] = (_Float16)W4[k * 16 + m];
    }
}

// mega1e: edge-centric agg64 into LDS fp32 acc; epilogue:
// (acc+self)*dis -> fp16 in place -> @W1+b1,relu -> sT -> @W2,*dis -> Z2.
__global__ __launch_bounds__(256, 4) void mega1e_kernel(
        const _Float16* __restrict__ hs, const int* __restrict__ bcur,
        const int* __restrict__ csr, const float* __restrict__ dis,
        const _Float16* __restrict__ W1t, const float* __restrict__ b1,
        const _Float16* __restrict__ W2t, _Float16* __restrict__ Z2, int N) {
    __shared__ float accf[128 * 64];                // 32KB
    _Float16* hAgg = (_Float16*)accf;               // fp16 image [0,16KB)
    _Float16* sTb  = ((_Float16*)accf) + 8192;      // sT region [16KB,28KB)
    int tid = threadIdx.x;
    int b = blockIdx.x;
    f32x4 z = {0.f, 0.f, 0.f, 0.f};
#pragma unroll
    for (int i = 0; i < 8; ++i)
        *(f32x4*)(accf + tid * 4 + i * 1024) = z;
    __syncthreads();
    int n = min(bcur[b], BCAP);
    const int* ecsr = csr + b * BCAP;
    int g = tid >> 3, q = tid & 7;
    int e = g;
    for (; e + 32 < n; e += 64) {
        int p0 = __builtin_nontemporal_load(ecsr + e);
        int p1 = __builtin_nontemporal_load(ecsr + e + 32);
        half8 v0 = *(const half8*)(hs + (size_t)(p0 & 0x1FFFF) * 64 + 8 * q);
        half8 v1 = *(const half8*)(hs + (size_t)(p1 & 0x1FFFF) * 64 + 8 * q);
        int d0 = (p0 >> 17) * 64 + 8 * q;
        int d1 = (p1 >> 17) * 64 + 8 * q;
#pragma unroll
        for (int j = 0; j < 8; ++j) atomicAdd(&accf[d0 + j], (float)v0[j]);
#pragma unroll
        for (int j = 0; j < 8; ++j) atomicAdd(&accf[d1 + j], (float)v1[j]);
    }
    for (; e < n; e += 32) {
        int p0 = __builtin_nontemporal_load(ecsr + e);
        half8 v0 = *(const half8*)(hs + (size_t)(p0 & 0x1FFFF) * 64 + 8 * q);
        int d0 = (p0 >> 17) * 64 + 8 * q;
#pragma unroll
        for (int j = 0; j < 8; ++j) atomicAdd(&accf[d0 + j], (float)v0[j]);
    }
    __syncthreads();
    // conversion: thread owns row rl=tid>>1, half hh=tid&1 (32 floats)
    int rl = tid >> 1, hh = tid & 1;
    int row = b * 128 + rl;
    float vals[32];
#pragma unroll
    for (int i = 0; i < 8; ++i) {
        f32x4 t = *(f32x4*)(accf + rl * 64 + hh * 32 + i * 4);
        vals[i * 4 + 0] = t.x; vals[i * 4 + 1] = t.y;
        vals[i * 4 + 2] = t.z; vals[i * 4 + 3] = t.w;
    }
    float dv = 0.f;
    half8 selfv[4] = {};
    if (row < N) {
        dv = dis[row];
#pragma unroll
        for (int k = 0; k < 4; ++k)
            selfv[k] = *(const half8*)(hs + (size_t)row * 64 + hh * 32 + k * 8);
    }
    __syncthreads();   // all accf reads complete before fp16 overwrite
#pragma unroll
    for (int k = 0; k < 4; ++k) {
        half8 hv;
#pragma unroll
        for (int j = 0; j < 8; ++j)
            hv[j] = (_Float16)((vals[k * 8 + j] + (float)selfv[k][j]) * dv);
        *(half8*)(hAgg + rl * 64 + hh * 32 + k * 8) = hv;
    }
    __syncthreads();
    // MFMA chains
    int wid = tid >> 6, lane = tid & 63;
    int quad = lane >> 4, m16 = lane & 15;
    int rbase = b * 128;
    _Float16* sT = sTb + wid * 1536;
#pragma unroll 1
    for (int tt = 0; tt < 2; ++tt) {
        int t = wid * 2 + tt;
        half8 a[2];
#pragma unroll
        for (int kt = 0; kt < 2; ++kt)
            a[kt] = *(const half8*)(hAgg + (t * 16 + m16) * 64 + kt * 32 + quad * 8);
#pragma unroll
        for (int ct = 0; ct < 6; ++ct) {
            f32x4 c = {0.f, 0.f, 0.f, 0.f};
#pragma unroll
            for (int kt = 0; kt < 2; ++kt) {
                half8 bb = *(const half8*)(W1t + (size_t)(ct * 16 + m16) * 64 + kt * 32 + quad * 8);
                c = __builtin_amdgcn_mfma_f32_16x16x32_f16(a[kt], bb, c, 0, 0, 0);
            }
            int col = ct * 16 + m16;
            float bv = b1[col];
#pragma unroll
            for (int r = 0; r < 4; ++r)
                sT[(quad * 4 + r) * 96 + col] = (_Float16)fmaxf(c[r] + bv, 0.f);
        }
        __syncthreads();
        half8 a2[3];
#pragma unroll
        for (int kt = 0; kt < 3; ++kt)
            a2[kt] = *(const half8*)(sT + m16 * 96 + kt * 32 + quad * 8);
        int obase = rbase + t * 16;
        float dvv[4];
#pragma unroll
        for (int r = 0; r < 4; ++r) {
            int orow = obase + quad * 4 + r;
            dvv[r] = (orow < N) ? dis[orow] : 0.f;
        }
#pragma unroll
        for (int ct = 0; ct < 4; ++ct) {
            f32x4 c = {0.f, 0.f, 0.f, 0.f};
#pragma unroll
            for (int kt = 0; kt < 3; ++kt) {
                half8 bb = *(const half8*)(W2t + (size_t)(ct * 16 + m16) * 96 + kt * 32 + quad * 8);
                c = __builtin_amdgcn_mfma_f32_16x16x32_f16(a2[kt], bb, c, 0, 0, 0);
            }
            int col = ct * 16 + m16;
#pragma unroll
            for (int r = 0; r < 4; ++r) {
                int orow = obase + quad * 4 + r;
                if (orow < N)
                    Z2[(size_t)orow * 64 + col] = (_Float16)(c[r] * dvv[r]);
            }
        }
        __syncthreads();
    }
}

// mega2e: edge-centric agg64; conversion applies +b2,relu; MFMA @W3 -> Z3.
__global__ __launch_bounds__(256, 4) void mega2e_kernel(
        const _Float16* __restrict__ hs, const int* __restrict__ bcur,
        const int* __restrict__ csr, const float* __restrict__ dis,
        const float* __restrict__ b2, const _Float16* __restrict__ W3t,
        _Float16* __restrict__ Z3, int N) {
    __shared__ float accf[128 * 64];
    _Float16* hAgg = (_Float16*)accf;
    int tid = threadIdx.x;
    int b = blockIdx.x;
    f32x4 z = {0.f, 0.f, 0.f, 0.f};
#pragma unroll
    for (int i = 0; i < 8; ++i)
        *(f32x4*)(accf + tid * 4 + i * 1024) = z;
    __syncthreads();
    int n = min(bcur[b], BCAP);
    const int* ecsr = csr + b * BCAP;
    int g = tid >> 3, q = tid & 7;
    int e = g;
    for (; e + 32 < n; e += 64) {
        int p0 = __builtin_nontemporal_load(ecsr + e);
        int p1 = __builtin_nontemporal_load(ecsr + e + 32);
        half8 v0 = *(const half8*)(hs + (size_t)(p0 & 0x1FFFF) * 64 + 8 * q);
        half8 v1 = *(const half8*)(hs + (size_t)(p1 & 0x1FFFF) * 64 + 8 * q);
        int d0 = (p0 >> 17) * 64 + 8 * q;
        int d1 = (p1 >> 17) * 64 + 8 * q;
#pragma unroll
        for (int j = 0; j < 8; ++j) atomicAdd(&accf[d0 + j], (float)v0[j]);
#pragma unroll
        for (int j = 0; j < 8; ++j) atomicAdd(&accf[d1 + j], (float)v1[j]);
    }
    for (; e < n; e += 32) {
        int p0 = __builtin_nontemporal_load(ecsr + e);
        half8 v0 = *(const half8*)(hs + (size_t)(p0 & 0x1FFFF) * 64 + 8 * q);
        int d0 = (p0 >> 17) * 64 + 8 * q;
#pragma unroll
        for (int j = 0; j < 8; ++j) atomicAdd(&accf[d0 + j], (float)v0[j]);
    }
    __syncthreads();
    int rl = tid >> 1, hh = tid & 1;
    int row = b * 128 + rl;
    float vals[32];
#pragma unroll
    for (int i = 0; i < 8; ++i) {
        f32x4 t = *(f32x4*)(accf + rl * 64 + hh * 32 + i * 4);
        vals[i * 4 + 0] = t.x; vals[i * 4 + 1] = t.y;
        vals[i * 4 + 2] = t.z; vals[i * 4 + 3] = t.w;
    }
    float dv = 0.f;
    half8 selfv[4] = {};
    if (row < N) {
        dv = dis[row];
#pragma unroll
        for (int k = 0; k < 4; ++k)
            selfv[k] = *(const half8*)(hs + (size_t)row * 64 + hh * 32 + k * 8);
    }
    f32x4 blo[8];
#pragma unroll
    for (int k = 0; k < 8; ++k)
        blo[k] = *(const f32x4*)(b2 + hh * 32 + k * 4);
    __syncthreads();
#pragma unroll
    for (int k = 0; k < 4; ++k) {
        half8 hv;
#pragma unroll
        for (int j = 0; j < 8; ++j) {
            float bb = ((const float*)blo)[k * 8 + j];
            hv[j] = (_Float16)fmaxf((vals[k * 8 + j] + (float)selfv[k][j]) * dv + bb, 0.f);
        }
        *(half8*)(hAgg + rl * 64 + hh * 32 + k * 8) = hv;
    }
    __syncthreads();
    int wid = tid >> 6, lane = tid & 63;
    int quad = lane >> 4, m16 = lane & 15;
    int rbase = b * 128;
#pragma unroll 1
    for (int tt = 0; tt < 2; ++tt) {
        int t = wid * 2 + tt;
        half8 a[2];
#pragma unroll
        for (int kt = 0; kt < 2; ++kt)
            a[kt] = *(const half8*)(hAgg + (t * 16 + m16) * 64 + kt * 32 + quad * 8);
        int obase = rbase + t * 16;
        float dvv[4];
#pragma unroll
        for (int r = 0; r < 4; ++r) {
            int orow = obase + quad * 4 + r;
            dvv[r] = (orow < N) ? dis[orow] : 0.f;
        }
#pragma unroll
        for (int ct = 0; ct < 2; ++ct) {
            f32x4 c = {0.f, 0.f, 0.f, 0.f};
#pragma unroll
            for (int kt = 0; kt < 2; ++kt) {
                half8 bb = *(const half8*)(W3t + (size_t)(ct * 16 + m16) * 64 + kt * 32 + quad * 8);
                c = __builtin_amdgcn_mfma_f32_16x16x32_f16(a[kt], bb, c, 0, 0, 0);
            }
            int col = ct * 16 + m16;
#pragma unroll
            for (int r = 0; r < 4; ++r) {
                int orow = obase + quad * 4 + r;
                if (orow < N)
                    Z3[(size_t)orow * 32 + col] = (_Float16)(c[r] * dvv[r]);
            }
        }
    }
}

// agg32e: edge-centric F=32 (4-lane groups); conversion +b3,relu; MFMA @W4.
__global__ __launch_bounds__(256, 4) void agg32e_kernel(
        const _Float16* __restrict__ hs, const int* __restrict__ bcur,
        const int* __restrict__ csr, const float* __restrict__ dis,
        const float* __restrict__ b3, const _Float16* __restrict__ W4t,
        _Float16* __restrict__ Z4, int N) {
    __shared__ float accf[128 * 32];   // 16KB
    _Float16* hT = (_Float16*)accf;    // fp16 image [0,8KB)
    int tid = threadIdx.x;
    int b = blockIdx.x;
    f32x4 z = {0.f, 0.f, 0.f, 0.f};
#pragma unroll
    for (int i = 0; i < 4; ++i)
        *(f32x4*)(accf + tid * 4 + i * 1024) = z;
    __syncthreads();
    int n = min(bcur[b], BCAP);
    const int* ecsr = csr + b * BCAP;
    int g = tid >> 2, q = tid & 3;
    int e = g;
    for (; e + 64 < n; e += 128) {
        int p0 = __builtin_nontemporal_load(ecsr + e);
        int p1 = __builtin_nontemporal_load(ecsr + e + 64);
        half8 v0 = *(const half8*)(hs + (size_t)(p0 & 0x1FFFF) * 32 + 8 * q);
        half8 v1 = *(const half8*)(hs + (size_t)(p1 & 0x1FFFF) * 32 + 8 * q);
        int d0 = (p0 >> 17) * 32 + 8 * q;
        int d1 = (p1 >> 17) * 32 + 8 * q;
#pragma unroll
        for (int j = 0; j < 8; ++j) atomicAdd(&accf[d0 + j], (float)v0[j]);
#pragma unroll
        for (int j = 0; j < 8; ++j) atomicAdd(&accf[d1 + j], (float)v1[j]);
    }
    for (; e < n; e += 64) {
        int p0 = __builtin_nontemporal_load(ecsr + e);
        half8 v0 = *(const half8*)(hs + (size_t)(p0 & 0x1FFFF) * 32 + 8 * q);
        int d0 = (p0 >> 17) * 32 + 8 * q;
#pragma unroll
        for (int j = 0; j < 8; ++j) atomicAdd(&accf[d0 + j], (float)v0[j]);
    }
    __syncthreads();
    int rl = tid >> 1, hh = tid & 1;
    int row = b * 128 + rl;
    float vals[16];
#pragma unroll
    for (int i = 0; i < 4; ++i) {
        f32x4 t = *(f32x4*)(accf + rl * 32 + hh * 16 + i * 4);
        vals[i * 4 + 0] = t.x; vals[i * 4 + 1] = t.y;
        vals[i * 4 + 2] = t.z; vals[i * 4 + 3] = t.w;
    }
    float dv = 0.f;
    half8 selfv[2] = {};
    if (row < N) {
        dv = dis[row];
#pragma unroll
        for (int k = 0; k < 2; ++k)
            selfv[k] = *(const half8*)(hs + (size_t)row * 32 + hh * 16 + k * 8);
    }
    __syncthreads();
#pragma unroll
    for (int k = 0; k < 2; ++k) {
        half8 hv;
#pragma unroll
        for (int j = 0; j < 8; ++j) {
            float bb = b3[hh * 16 + k * 8 + j];
            hv[j] = (_Float16)fmaxf((vals[k * 8 + j] + (float)selfv[k][j]) * dv + bb, 0.f);
        }
        *(half8*)(hT + rl * 32 + hh * 16 + k * 8) = hv;
    }
    __syncthreads();
    int wid = tid >> 6, lane = tid & 63;
    int quad = lane >> 4, m16 = lane & 15;
    int rbase = b * 128;
#pragma unroll 1
    for (int tt = 0; tt < 2; ++tt) {
        int t = wid * 2 + tt;
        half8 a = *(const half8*)(hT + (t * 16 + m16) * 32 + quad * 8);
        half8 bb = *(const half8*)(W4t + m16 * 32 + quad * 8);
        f32x4 c = {0.f, 0.f, 0.f, 0.f};
        c = __builtin_amdgcn_mfma_f32_16x16x32_f16(a, bb, c, 0, 0, 0);
        int obase = rbase + t * 16;
#pragma unroll
        for (int r = 0; r < 4; ++r) {
            int orow = obase + quad * 4 + r;
            if (orow < N)
                Z4[(size_t)orow * 16 + m16] = (_Float16)(c[r] * dis[orow]);
        }
    }
}

// finale: edge-centric F=16 (2-lane groups); out = (acc+self)*dis + b4, fp32.
__global__ __launch_bounds__(256, 4) void finale_kernel(
        const _Float16* __restrict__ hs, const int* __restrict__ bcur,
        const int* __restrict__ csr, const float* __restrict__ dis,
        const float* __restrict__ b4, float* __restrict__ outp, int N) {
    __shared__ float accf[128 * 16];   // 8KB
    int tid = threadIdx.x;
    int b = blockIdx.x;
    f32x4 z = {0.f, 0.f, 0.f, 0.f};
#pragma unroll
    for (int i = 0; i < 2; ++i)
        *(f32x4*)(accf + tid * 4 + i * 1024) = z;
    __syncthreads();
    int n = min(bcur[b], BCAP);
    const int* ecsr = csr + b * BCAP;
    int g = tid >> 1, q = tid & 1;
    int e = g;
    for (; e + 128 < n; e += 256) {
        int p0 = __builtin_nontemporal_load(ecsr + e);
        int p1 = __builtin_nontemporal_load(ecsr + e + 128);
        half8 v0 = *(const half8*)(hs + (size_t)(p0 & 0x1FFFF) * 16 + 8 * q);
        half8 v1 = *(const half8*)(hs + (size_t)(p1 & 0x1FFFF) * 16 + 8 * q);
        int d0 = (p0 >> 17) * 16 + 8 * q;
        int d1 = (p1 >> 17) * 16 + 8 * q;
#pragma unroll
        for (int j = 0; j < 8; ++j) atomicAdd(&accf[d0 + j], (float)v0[j]);
#pragma unroll
        for (int j = 0; j < 8; ++j) atomicAdd(&accf[d1 + j], (float)v1[j]);
    }
    for (; e < n; e += 128) {
        int p0 = __builtin_nontemporal_load(ecsr + e);
        half8 v0 = *(const half8*)(hs + (size_t)(p0 & 0x1FFFF) * 16 + 8 * q);
        int d0 = (p0 >> 17) * 16 + 8 * q;
#pragma unroll
        for (int j = 0; j < 8; ++j) atomicAdd(&accf[d0 + j], (float)v0[j]);
    }
    __syncthreads();
    int rl = tid >> 1, hh = tid & 1;
    int row = b * 128 + rl;
    if (row >= N) return;
    float dv = dis[row];
    half8 selfv = *(const half8*)(hs + (size_t)row * 16 + hh * 8);
    float4 o0, o1;
    float* av = accf + rl * 16 + hh * 8;
    o0.x = (av[0] + (float)selfv[0]) * dv + b4[hh * 8 + 0];
    o0.y = (av[1] + (float)selfv[1]) * dv + b4[hh * 8 + 1];
    o0.z = (av[2] + (float)selfv[2]) * dv + b4[hh * 8 + 2];
    o0.w = (av[3] + (float)selfv[3]) * dv + b4[hh * 8 + 3];
    o1.x = (av[4] + (float)selfv[4]) * dv + b4[hh * 8 + 4];
    o1.y = (av[5] + (float)selfv[5]) * dv + b4[hh * 8 + 5];
    o1.z = (av[6] + (float)selfv[6]) * dv + b4[hh * 8 + 6];
    o1.w = (av[7] + (float)selfv[7]) * dv + b4[hh * 8 + 7];
    *(float4*)(outp + (size_t)row * 16 + hh * 8) = o0;
    *(float4*)(outp + (size_t)row * 16 + hh * 8 + 4) = o1;
}

static inline int cdiv(long long a, int b) { return (int)((a + b - 1) / b); }

extern "C" void kernel_launch(void* const* d_in, const int* in_sizes, int n_in,
                              void* d_out, int out_size, void* d_ws, size_t ws_size,
                              hipStream_t stream) {
    const float* x  = (const float*)d_in[0];
    const int*   ei = (const int*)d_in[1];
    const float* W1 = (const float*)d_in[2];
    const float* b1 = (const float*)d_in[3];
    const float* W2 = (const float*)d_in[4];
    const float* b2 = (const float*)d_in[5];
    const float* W3 = (const float*)d_in[6];
    const float* b3 = (const float*)d_in[7];
    const float* W4 = (const float*)d_in[8];
    const float* b4 = (const float*)d_in[9];
    float* out = (float*)d_out;

    int N = in_sizes[0] / 64;   // 100000
    int E = in_sizes[1] / 2;    // 1600000
    const int* src = ei;
    const int* dst = ei + E;

    int*   bcur = (int*)d_ws;                        // 788
    int*   csr  = bcur + 788;                        // NBUCK*BCAP packed edges
    float* dis  = (float*)(csr + NBUCK * BCAP);      // 100096
    _Float16* hP = (_Float16*)(dis + 100096);        // N*64 halfs
    _Float16* hQ = hP + (size_t)N * 64;              // N*64 halfs
    _Float16* wt = hQ + (size_t)N * 64;              // 14848 halfs
    int*   bsort = (int*)hP;   // NBUCK*BCAP ints, dead before hP's first write

    // --- build ---
    wprep_kernel<<<cdiv(14848, TPB), TPB, 0, stream>>>(W1, W2, W3, W4, wt, bcur);
    bscatter_kernel<<<cdiv(E, CHUNK), 512, 0, stream>>>(src, dst, bcur, bsort, E);
    bbuild_kernel<<<NBUCK, 256, 0, stream>>>(bcur, bsort, csr, dis,
                                             (const float4*)x, hQ, N);

    // --- mega1e: hP = Z2 ---
    mega1e_kernel<<<NBUCK, 256, 0, stream>>>(
        hQ, bcur, csr, dis, wt + 0, b1, wt + 6144, hP, N);

    // --- mega2e: hQ = Z3 ---
    mega2e_kernel<<<NBUCK, 256, 0, stream>>>(
        hP, bcur, csr, dis, b2, wt + 12288, hQ, N);

    // --- agg32e: hP = Z4 ---
    agg32e_kernel<<<NBUCK, 256, 0, stream>>>(
        hQ, bcur, csr, dis, b3, wt + 14336, hP, N);

    // --- finale ---
    finale_kernel<<<NBUCK, 256, 0, stream>>>(
        hP, bcur, csr, dis, b4, out, N);
}